// Round 7
// baseline (201.827 us; speedup 1.0000x reference)
//
#include <hip/hip_runtime.h>
#include <hip/hip_bf16.h>
#include <hip/hip_cooperative_groups.h>

namespace cg = cooperative_groups;

// proto_net_loss. Preferred: ONE cooperative kernel (phases grid-synced).
// Fallback (if coop launch refused): 5 dispatches using the SAME phase bodies.
//  phase0: W1T/W2T bf16 transposed weights (20 tile-jobs)
//  phase1: H(bf16) = X @ W1, 4-wave K-split per 16-row strip + BN partials (640 jobs)
//  phase2: BN scale/shift (1 block)
//  phase3: Z(bf16) = relu(H*sc+sh) @ W2 + f32 row norms (640 jobs)
//  phase4: D = n1[i]+n2[j]-2*Z1@Z2^T (1024 tiles)

#define LAT 512
#define HID 128
#define EPSV 1e-5f
#define SMEM_BYTES (4 * 64 * 33 * 4)  // 33792

typedef __attribute__((ext_vector_type(8))) short bf16x8;
typedef __attribute__((ext_vector_type(4))) float f32x4;

__device__ __forceinline__ unsigned short f2bf(float x) {  // RTNE
  unsigned int u = __builtin_bit_cast(unsigned int, x);
  return (unsigned short)((u + 0x7fffu + ((u >> 16) & 1u)) >> 16);
}
__device__ __forceinline__ float bf2f(unsigned short h) {
  unsigned int u = ((unsigned int)h) << 16;
  return __builtin_bit_cast(float, u);
}

// ---------------- phase 0: tiled transpose f32 -> bf16 ----------------
__device__ __forceinline__ void ph_prep(char* smem, int bi, int tid,
                                        const float* __restrict__ W1,
                                        const float* __restrict__ W2,
                                        unsigned short* __restrict__ W1T,
                                        unsigned short* __restrict__ W2T) {
  float(*T)[65] = (float(*)[65])smem;
  const float* src;
  unsigned short* dst;
  int K, N, tk, tn;
  if (bi < 16) { src = W1; dst = W1T; K = LAT; N = HID; tk = bi >> 1; tn = bi & 1; }
  else { bi -= 16; src = W2; dst = W2T; K = HID; N = HID; tk = bi >> 1; tn = bi & 1; }
  const int k0 = tk * 64, n0 = tn * 64;
  {
    const int rr = tid >> 4, cc = (tid & 15) * 4;
#pragma unroll
    for (int i = 0; i < 4; ++i) {
      const int r = rr + i * 16;
      const float4 v = *(const float4*)(src + (size_t)(k0 + r) * N + n0 + cc);
      T[cc + 0][r] = v.x; T[cc + 1][r] = v.y; T[cc + 2][r] = v.z; T[cc + 3][r] = v.w;
    }
  }
  __syncthreads();
  {
    const int nn = tid >> 2, q = (tid & 3) * 16;
    unsigned short* dp = dst + (size_t)(n0 + nn) * K + k0 + q;
#pragma unroll
    for (int j = 0; j < 4; ++j) {
      ushort4 o = {f2bf(T[nn][q + j * 4 + 0]), f2bf(T[nn][q + j * 4 + 1]),
                   f2bf(T[nn][q + j * 4 + 2]), f2bf(T[nn][q + j * 4 + 3])};
      *(ushort4*)(dp + j * 4) = o;
    }
  }
}

// ---------------- phase 1: gemm1 strip (16 rows), 4-wave K-split ----------------
__device__ __forceinline__ void ph_gemm1(char* smem, int job, int tid,
                                         const float* __restrict__ X1,
                                         const float* __restrict__ X2,
                                         int nx, int nb1,
                                         const unsigned short* __restrict__ W1T,
                                         unsigned short* __restrict__ Hb,
                                         float* __restrict__ pS,
                                         float* __restrict__ pQ) {
  float(*part)[64][33] = (float(*)[64][33])smem;
  const int w = tid >> 6, lane = tid & 63;
  const int l15 = lane & 15, lq = lane >> 4, lk8 = lq * 8;
  const int row0 = job * 16;
  const bool set1 = job < nb1;
  const float* X = set1 ? X1 : X2;
  const int xrow = set1 ? row0 : row0 - nx;
  const int kb = w * 128;
  const float* xptr = X + (size_t)(xrow + l15) * LAT + kb + lk8;

  f32x4 acc[8];
#pragma unroll
  for (int f = 0; f < 8; ++f) acc[f] = (f32x4){0.f, 0.f, 0.f, 0.f};
  float4 xv[4][2];
#pragma unroll
  for (int s = 0; s < 4; ++s) {
    xv[s][0] = *(const float4*)(xptr + s * 32);
    xv[s][1] = *(const float4*)(xptr + s * 32 + 4);
  }
#pragma unroll
  for (int s = 0; s < 4; ++s) {
    const float vv[8] = {xv[s][0].x, xv[s][0].y, xv[s][0].z, xv[s][0].w,
                         xv[s][1].x, xv[s][1].y, xv[s][1].z, xv[s][1].w};
    bf16x8 bfr;
#pragma unroll
    for (int i = 0; i < 8; ++i) bfr[i] = (short)f2bf(vv[i]);
    const int k = kb + s * 32 + lk8;
#pragma unroll
    for (int f = 0; f < 8; ++f) {
      const bf16x8 afr = *(const bf16x8*)(W1T + (size_t)(f * 16 + l15) * LAT + k);
      acc[f] = __builtin_amdgcn_mfma_f32_16x16x32_bf16(afr, bfr, acc[f], 0, 0, 0);
    }
  }
#pragma unroll
  for (int f = 0; f < 8; ++f)
    *(f32x4*)&part[w][lq * 16 + l15][f * 4] = acc[f];
  __syncthreads();

  const int r = tid >> 4;          // 0..15
  const int cq8 = (tid & 15) * 8;  // 0..120
  const int f = cq8 >> 4;
  const int lq0 = (cq8 >> 2) & 3;
  f32x4 h0 = *(const f32x4*)&part[0][lq0 * 16 + r][f * 4];
  f32x4 h1 = *(const f32x4*)&part[0][(lq0 + 1) * 16 + r][f * 4];
#pragma unroll
  for (int ww = 1; ww < 4; ++ww) {
    h0 += *(const f32x4*)&part[ww][lq0 * 16 + r][f * 4];
    h1 += *(const f32x4*)&part[ww][(lq0 + 1) * 16 + r][f * 4];
  }
  {
    ushort4 z0 = {f2bf(h0[0]), f2bf(h0[1]), f2bf(h0[2]), f2bf(h0[3])};
    ushort4 z1 = {f2bf(h1[0]), f2bf(h1[1]), f2bf(h1[2]), f2bf(h1[3])};
    unsigned short* hp = Hb + (size_t)(row0 + r) * HID + cq8;
    *(ushort4*)hp = z0;
    *(ushort4*)(hp + 4) = z1;
  }
  __syncthreads();
  float(*sS)[132] = (float(*)[132]) & part[0][0][0];
  float(*sQ)[132] = (float(*)[132]) & part[1][0][0];
  *(f32x4*)&sS[r][cq8] = h0;
  *(f32x4*)&sS[r][cq8 + 4] = h1;
  *(f32x4*)&sQ[r][cq8] = h0 * h0;
  *(f32x4*)&sQ[r][cq8 + 4] = h1 * h1;
  __syncthreads();
  if (tid < HID) {
    float s = 0.f, q = 0.f;
#pragma unroll
    for (int rr = 0; rr < 16; ++rr) { s += sS[rr][tid]; q += sQ[rr][tid]; }
    pS[(size_t)job * HID + tid] = s;
    pQ[(size_t)job * HID + tid] = q;
  }
  __syncthreads();
}

// ---------------- phase 2: BN finalize (single block, 256 threads) ----------------
__device__ __forceinline__ void ph_fin(char* smem, int tid,
                                       const float* __restrict__ pS,
                                       const float* __restrict__ pQ,
                                       const float* __restrict__ gamma,
                                       const float* __restrict__ beta,
                                       float* __restrict__ sc1, float* __restrict__ sh1,
                                       float* __restrict__ sc2, float* __restrict__ sh2,
                                       int nb1, int njob, float n1c, float n2c) {
  f32x4* sA = (f32x4*)smem;  // [8][32] each
  f32x4* qA = sA + 256;
  f32x4* sB = qA + 256;
  f32x4* qB = sB + 256;  // 16 KB total
  const int chunk = tid >> 5, cq = tid & 31;
  const int len1 = nb1 / 8, len2 = (njob - nb1) / 8;
  {
    f32x4 s = {0.f, 0.f, 0.f, 0.f}, q = {0.f, 0.f, 0.f, 0.f};
    const int r0 = chunk * len1;
    for (int r = 0; r < len1; ++r) {
      s += *(const f32x4*)(pS + (size_t)(r0 + r) * HID + cq * 4);
      q += *(const f32x4*)(pQ + (size_t)(r0 + r) * HID + cq * 4);
    }
    sA[chunk * 32 + cq] = s; qA[chunk * 32 + cq] = q;
  }
  {
    f32x4 s = {0.f, 0.f, 0.f, 0.f}, q = {0.f, 0.f, 0.f, 0.f};
    const int r0 = nb1 + chunk * len2;
    for (int r = 0; r < len2; ++r) {
      s += *(const f32x4*)(pS + (size_t)(r0 + r) * HID + cq * 4);
      q += *(const f32x4*)(pQ + (size_t)(r0 + r) * HID + cq * 4);
    }
    sB[chunk * 32 + cq] = s; qB[chunk * 32 + cq] = q;
  }
  __syncthreads();
  if (tid < 64) {
    const int set = tid >> 5, c = tid & 31;
    const f32x4* ps = set ? sB : sA;
    const f32x4* pq = set ? qB : qA;
    f32x4 s = {0.f, 0.f, 0.f, 0.f}, q = {0.f, 0.f, 0.f, 0.f};
#pragma unroll
    for (int ch = 0; ch < 8; ++ch) { s += ps[ch * 32 + c]; q += pq[ch * 32 + c]; }
    const float n = set ? n2c : n1c;
    float* sc = set ? sc2 : sc1;
    float* sh = set ? sh2 : sh1;
#pragma unroll
    for (int e = 0; e < 4; ++e) {
      const int col = c * 4 + e;
      const float mean = s[e] / n;
      const float var = q[e] / n - mean * mean;
      const float rstd = rsqrtf(var + EPSV);
      const float scale = gamma[col] * rstd;
      const float shift = beta[col] - mean * scale;
      sc[col] = scale;
      sh[col] = shift;
    }
  }
}

// ---------------- phase 3: gemm2 strip (16 rows), 4-wave frag-split ----------------
__device__ __forceinline__ void ph_gemm2(char* smem, int job, int tid,
                                         const unsigned short* __restrict__ Hb, int nb1,
                                         const unsigned short* __restrict__ W2T,
                                         const float* __restrict__ sc1,
                                         const float* __restrict__ sh1,
                                         const float* __restrict__ sc2,
                                         const float* __restrict__ sh2,
                                         unsigned short* __restrict__ Zb,
                                         float* __restrict__ nrm) {
  float(*sN)[16] = (float(*)[16])smem;
  const int w = tid >> 6, lane = tid & 63;
  const int l15 = lane & 15, lq = lane >> 4, lk8 = lq * 8;
  const int row0 = job * 16;
  const bool set1 = job < nb1;
  const float* sc = set1 ? sc1 : sc2;
  const float* sh = set1 ? sh1 : sh2;
  const unsigned short* hptr = Hb + (size_t)(row0 + l15) * HID + lk8;
  f32x4 acc2[2];
  acc2[0] = (f32x4){0.f, 0.f, 0.f, 0.f};
  acc2[1] = (f32x4){0.f, 0.f, 0.f, 0.f};
#pragma unroll
  for (int s = 0; s < 4; ++s) {
    const int k = s * 32 + lk8;
    const bf16x8 hv = *(const bf16x8*)(hptr + s * 32);
    const float4 c0 = *(const float4*)(sc + k);
    const float4 c1 = *(const float4*)(sc + k + 4);
    const float4 d0 = *(const float4*)(sh + k);
    const float4 d1 = *(const float4*)(sh + k + 4);
    const float ccv[8] = {c0.x, c0.y, c0.z, c0.w, c1.x, c1.y, c1.z, c1.w};
    const float ddv[8] = {d0.x, d0.y, d0.z, d0.w, d1.x, d1.y, d1.z, d1.w};
    bf16x8 bfr;
#pragma unroll
    for (int i = 0; i < 8; ++i) {
      const float a = fmaxf(fmaf(bf2f((unsigned short)hv[i]), ccv[i], ddv[i]), 0.f);
      bfr[i] = (short)f2bf(a);
    }
#pragma unroll
    for (int ff = 0; ff < 2; ++ff) {
      const int f = w * 2 + ff;
      const bf16x8 afr = *(const bf16x8*)(W2T + (size_t)(f * 16 + l15) * HID + k);
      acc2[ff] = __builtin_amdgcn_mfma_f32_16x16x32_bf16(afr, bfr, acc2[ff], 0, 0, 0);
    }
  }
  float rn = 0.f;
#pragma unroll
  for (int ff = 0; ff < 2; ++ff) {
    rn += acc2[ff][0] * acc2[ff][0] + acc2[ff][1] * acc2[ff][1] +
          acc2[ff][2] * acc2[ff][2] + acc2[ff][3] * acc2[ff][3];
    const int f = w * 2 + ff;
    ushort4 z4 = {f2bf(acc2[ff][0]), f2bf(acc2[ff][1]),
                  f2bf(acc2[ff][2]), f2bf(acc2[ff][3])};
    *(ushort4*)(Zb + (size_t)(row0 + l15) * HID + f * 16 + lq * 4) = z4;
  }
  rn += __shfl_xor(rn, 16, 64);
  rn += __shfl_xor(rn, 32, 64);
  if (lane < 16) sN[w][l15] = rn;
  __syncthreads();
  if (w == 0 && lane < 16)
    nrm[row0 + l15] = sN[0][l15] + sN[1][l15] + sN[2][l15] + sN[3][l15];
  __syncthreads();
}

// ---------------- phase 4: one 128x128 dist tile ----------------
__device__ __forceinline__ void ph_dist(int t4, int tid,
                                        const unsigned short* __restrict__ Zb,
                                        const float* __restrict__ nrm,
                                        float* __restrict__ D, int nx, int ny) {
  const int wid = tid >> 6, lane = tid & 63;
  const int wr = wid >> 1, wc = wid & 1;
  const int l15 = lane & 15, lq = lane >> 4, lk = lq * 8;
  const int ntx = ny >> 7;
  const int tby = t4 / ntx, tbx = t4 - tby * ntx;
  const int rowB = tby * 128 + wr * 64;
  const int colB = tbx * 128 + wc * 64;
  const float* n1 = nrm;
  const float* n2 = nrm + nx;
  const unsigned short* Z1b = Zb;
  const unsigned short* Z2b = Zb + (size_t)nx * HID;
  const unsigned short* Arow = Z1b + (size_t)(rowB + l15) * HID + lk;
  const unsigned short* Brow = Z2b + (size_t)(colB + l15) * HID + lk;
  f32x4 acc[4][4];
#pragma unroll
  for (int i = 0; i < 4; ++i)
#pragma unroll
    for (int j = 0; j < 4; ++j) acc[i][j] = (f32x4){0.f, 0.f, 0.f, 0.f};
#pragma unroll
  for (int s = 0; s < 4; ++s) {
    bf16x8 a[4], b[4];
#pragma unroll
    for (int i = 0; i < 4; ++i)
      a[i] = *(const bf16x8*)(Arow + (size_t)i * 16 * HID + s * 32);
#pragma unroll
    for (int j = 0; j < 4; ++j)
      b[j] = *(const bf16x8*)(Brow + (size_t)j * 16 * HID + s * 32);
#pragma unroll
    for (int i = 0; i < 4; ++i)
#pragma unroll
      for (int j = 0; j < 4; ++j)
        acc[i][j] = __builtin_amdgcn_mfma_f32_16x16x32_bf16(b[j], a[i], acc[i][j], 0, 0, 0);
  }
  const int cq = lq * 4;
  float na[4];
#pragma unroll
  for (int i = 0; i < 4; ++i) na[i] = n1[rowB + i * 16 + l15];
#pragma unroll
  for (int j = 0; j < 4; ++j) {
    const float4 nbv = *(const float4*)(n2 + colB + j * 16 + cq);
#pragma unroll
    for (int i = 0; i < 4; ++i) {
      float4 o;
      o.x = na[i] + nbv.x - 2.f * acc[i][j][0];
      o.y = na[i] + nbv.y - 2.f * acc[i][j][1];
      o.z = na[i] + nbv.z - 2.f * acc[i][j][2];
      o.w = na[i] + nbv.w - 2.f * acc[i][j][3];
      *(float4*)(D + (size_t)(rowB + i * 16 + l15) * (size_t)ny + colB + j * 16 + cq) = o;
    }
  }
}

// ================= cooperative mega-kernel =================
__global__ __launch_bounds__(256, 2) void k_mega(
    const float* __restrict__ X1, const float* __restrict__ X2,
    const float* __restrict__ W1, const float* __restrict__ W2,
    const float* __restrict__ gamma, const float* __restrict__ beta,
    unsigned short* W1T, unsigned short* W2T,
    unsigned short* Hb, unsigned short* Zb,
    float* pS, float* pQ,
    float* sc1, float* sh1, float* sc2, float* sh2,
    float* nrm, float* D, int nx, int ny) {
  cg::grid_group gg = cg::this_grid();
  __shared__ __align__(16) char smem[SMEM_BYTES];
  const int tid = threadIdx.x;
  const int bid = (int)blockIdx.x;
  const int G = (int)gridDim.x;
  const int nb1 = nx / 16;
  const int njob = (nx + ny) / 16;
  const int ntiles = (nx >> 7) * (ny >> 7);

  if (bid < 20) ph_prep(smem, bid, tid, W1, W2, W1T, W2T);
  gg.sync();
  for (int job = bid; job < njob; job += G)
    ph_gemm1(smem, job, tid, X1, X2, nx, nb1, W1T, Hb, pS, pQ);
  gg.sync();
  if (bid == 0)
    ph_fin(smem, tid, pS, pQ, gamma, beta, sc1, sh1, sc2, sh2,
           nb1, njob, (float)nx, (float)ny);
  gg.sync();
  for (int job = bid; job < njob; job += G)
    ph_gemm2(smem, job, tid, Hb, nb1, W2T, sc1, sh1, sc2, sh2, Zb, nrm);
  gg.sync();
  for (int t4 = bid; t4 < ntiles; t4 += G)
    ph_dist(t4, tid, Zb, nrm, D, nx, ny);
}

// ================= fallback standalone kernels =================
__global__ __launch_bounds__(256) void k_prep(const float* __restrict__ W1,
                                              const float* __restrict__ W2,
                                              unsigned short* W1T, unsigned short* W2T) {
  __shared__ __align__(16) char smem[SMEM_BYTES];
  ph_prep(smem, (int)blockIdx.x, (int)threadIdx.x, W1, W2, W1T, W2T);
}
__global__ __launch_bounds__(256) void k_gemm1(const float* __restrict__ X1,
                                               const float* __restrict__ X2, int nx,
                                               const unsigned short* __restrict__ W1T,
                                               unsigned short* Hb, float* pS, float* pQ,
                                               int nb1) {
  __shared__ __align__(16) char smem[SMEM_BYTES];
  ph_gemm1(smem, (int)blockIdx.x, (int)threadIdx.x, X1, X2, nx, nb1, W1T, Hb, pS, pQ);
}
__global__ __launch_bounds__(256) void k_finalize(const float* __restrict__ pS,
                                                  const float* __restrict__ pQ,
                                                  const float* __restrict__ gamma,
                                                  const float* __restrict__ beta,
                                                  float* sc1, float* sh1,
                                                  float* sc2, float* sh2,
                                                  int nb1, int njob, float n1c, float n2c) {
  __shared__ __align__(16) char smem[SMEM_BYTES];
  ph_fin(smem, (int)threadIdx.x, pS, pQ, gamma, beta, sc1, sh1, sc2, sh2,
         nb1, njob, n1c, n2c);
}
__global__ __launch_bounds__(256) void k_gemm2(const unsigned short* __restrict__ Hb,
                                               int nb1,
                                               const unsigned short* __restrict__ W2T,
                                               const float* sc1, const float* sh1,
                                               const float* sc2, const float* sh2,
                                               unsigned short* Zb, float* nrm) {
  __shared__ __align__(16) char smem[SMEM_BYTES];
  ph_gemm2(smem, (int)blockIdx.x, (int)threadIdx.x, Hb, nb1, W2T,
           sc1, sh1, sc2, sh2, Zb, nrm);
}
__global__ __launch_bounds__(256) void k_dist(const unsigned short* __restrict__ Zb,
                                              const float* __restrict__ nrm,
                                              float* D, int nx, int ny) {
  ph_dist((int)blockIdx.x, (int)threadIdx.x, Zb, nrm, D, nx, ny);
}

extern "C" void kernel_launch(void* const* d_in, const int* in_sizes, int n_in,
                              void* d_out, int out_size, void* d_ws, size_t ws_size,
                              hipStream_t stream) {
  const float* variations = (const float*)d_in[0];
  const float* exemplar   = (const float*)d_in[1];
  const float* w1         = (const float*)d_in[2];
  const float* gamma      = (const float*)d_in[3];
  const float* beta       = (const float*)d_in[4];
  const float* w2         = (const float*)d_in[5];
  float* D = (float*)d_out;

  int nx = in_sizes[0] / LAT;   // 8192
  int ny = in_sizes[1] / LAT;   // 2048
  const int nrows = nx + ny;    // 10240
  const int njob = nrows / 16;  // 640
  const int nb1 = nx / 16;      // 512
  const int ntiles = (nx >> 7) * (ny >> 7);  // 1024

  char* p = (char*)d_ws;
  unsigned short* Hb  = (unsigned short*)p; p += (size_t)nrows * HID * 2;
  unsigned short* Zb  = (unsigned short*)p; p += (size_t)nrows * HID * 2;
  unsigned short* W1T = (unsigned short*)p; p += (size_t)LAT * HID * 2;
  unsigned short* W2T = (unsigned short*)p; p += (size_t)HID * HID * 2;
  float* pS = (float*)p;  p += (size_t)njob * HID * 4;
  float* pQ = (float*)p;  p += (size_t)njob * HID * 4;
  float* sc1 = (float*)p; p += HID * 4;
  float* sh1 = (float*)p; p += HID * 4;
  float* sc2 = (float*)p; p += HID * 4;
  float* sh2 = (float*)p; p += HID * 4;
  float* nrmAll = (float*)p; p += (size_t)nrows * 4;

  // ---- try cooperative mega-kernel with runtime-validated grid ----
  hipError_t err = hipErrorUnknown;
  int occ = 0, cus = 0, dev = 0;
  (void)hipGetDevice(&dev);
  (void)hipDeviceGetAttribute(&cus, hipDeviceAttributeMultiprocessorCount, dev);
  (void)hipOccupancyMaxActiveBlocksPerMultiprocessor(&occ, k_mega, 256, 0);
  if (occ > 0 && cus > 0) {
    int grid = occ * cus;
    if (grid > 1024) grid = 1024;
    void* args[] = {&variations, &exemplar, &w1, &w2, &gamma, &beta,
                    &W1T, &W2T, &Hb, &Zb, &pS, &pQ,
                    &sc1, &sh1, &sc2, &sh2, &nrmAll, &D, &nx, &ny};
    for (int g = grid; g >= 64; g >>= 1) {
      err = hipLaunchCooperativeKernel((const void*)k_mega, dim3(g), dim3(256),
                                       args, 0, stream);
      if (err == hipSuccess) break;
      (void)hipGetLastError();  // clear sticky error
    }
  }
  if (err == hipSuccess) return;

  // ---- fallback: 5 plain dispatches (same phase bodies) ----
  k_prep<<<20, 256, 0, stream>>>(w1, w2, W1T, W2T);
  k_gemm1<<<njob, 256, 0, stream>>>(variations, exemplar, nx, W1T, Hb, pS, pQ, nb1);
  k_finalize<<<1, 256, 0, stream>>>(pS, pQ, gamma, beta, sc1, sh1, sc2, sh2,
                                    nb1, njob, (float)nx, (float)ny);
  k_gemm2<<<njob, 256, 0, stream>>>(Hb, nb1, W2T, sc1, sh1, sc2, sh2, Zb, nrmAll);
  k_dist<<<ntiles, 256, 0, stream>>>(Zb, nrmAll, D, nx, ny);
}

// Round 8
// 94.290 us; speedup vs baseline: 2.1405x; 2.1405x over previous
//
#include <hip/hip_runtime.h>
#include <hip/hip_bf16.h>

// proto_net_loss, 4 dispatches (was 5):
//  prep:   W1T/W2T bf16 transposed weights (tiled, coalesced) + ticket reset
//  gemm1:  H(bf16) = X @ W1 (160 blocks x 4 waves, wave = 16 rows full-K)
//          + fused BN partial stats + LAST-BLOCK inline finalize (sc/sh)
//  gemm2:  Z(bf16) = relu(H*sc+sh) @ W2 + f32 row norms (160 blocks)
//  dist:   D = n1[i]+n2[j]-2*Z1@Z2^T, LDS-staged epilogue for wide store segments

#define LAT 512
#define HID 128
#define EPSV 1e-5f

typedef __attribute__((ext_vector_type(8))) short bf16x8;
typedef __attribute__((ext_vector_type(4))) float f32x4;

__device__ __forceinline__ unsigned short f2bf(float x) {  // RTNE
  unsigned int u = __builtin_bit_cast(unsigned int, x);
  return (unsigned short)((u + 0x7fffu + ((u >> 16) & 1u)) >> 16);
}
__device__ __forceinline__ float bf2f(unsigned short h) {
  unsigned int u = ((unsigned int)h) << 16;
  return __builtin_bit_cast(float, u);
}

// ---------------- prep: tiled transpose f32 -> bf16 + ticket reset ----------------
__global__ __launch_bounds__(256) void k_prep(const float* __restrict__ W1,
                                              const float* __restrict__ W2,
                                              unsigned short* __restrict__ W1T,
                                              unsigned short* __restrict__ W2T,
                                              unsigned int* __restrict__ ticket) {
  __shared__ float T[64][65];
  const int t = threadIdx.x;
  int bi = blockIdx.x;
  if (bi == 0 && t == 0) *ticket = 0u;
  const float* src;
  unsigned short* dst;
  int K, N, tk, tn;
  if (bi < 16) { src = W1; dst = W1T; K = LAT; N = HID; tk = bi >> 1; tn = bi & 1; }
  else { bi -= 16; src = W2; dst = W2T; K = HID; N = HID; tk = bi >> 1; tn = bi & 1; }
  const int k0 = tk * 64, n0 = tn * 64;
  {
    const int rr = t >> 4, cc = (t & 15) * 4;
#pragma unroll
    for (int i = 0; i < 4; ++i) {
      const int r = rr + i * 16;
      const float4 v = *(const float4*)(src + (size_t)(k0 + r) * N + n0 + cc);
      T[cc + 0][r] = v.x; T[cc + 1][r] = v.y; T[cc + 2][r] = v.z; T[cc + 3][r] = v.w;
    }
  }
  __syncthreads();
  {
    const int nn = t >> 2, q = (t & 3) * 16;
    unsigned short* dp = dst + (size_t)(n0 + nn) * K + k0 + q;
#pragma unroll
    for (int j = 0; j < 4; ++j) {
      ushort4 o = {f2bf(T[nn][q + j * 4 + 0]), f2bf(T[nn][q + j * 4 + 1]),
                   f2bf(T[nn][q + j * 4 + 2]), f2bf(T[nn][q + j * 4 + 3])};
      *(ushort4*)(dp + j * 4) = o;
    }
  }
}

// ---------------- gemm1: 4 waves x 16 rows, full K=512; stats; last-block finalize ----
__global__ __launch_bounds__(256) void k_gemm1(
    const float* __restrict__ X1, const float* __restrict__ X2, int nx,
    const unsigned short* __restrict__ W1T, unsigned short* __restrict__ H,
    float* __restrict__ pS, float* __restrict__ pQ, int nb1, int nblk,
    const float* __restrict__ gamma, const float* __restrict__ beta,
    float* __restrict__ sc1, float* __restrict__ sh1,
    float* __restrict__ sc2, float* __restrict__ sh2,
    unsigned int* __restrict__ ticket, float n1c, float n2c) {
  __shared__ float sS[16][HID], sQ[16][HID];
  __shared__ unsigned int lastFlag;
  const int tid = threadIdx.x, wid = tid >> 6, lane = tid & 63;
  const int l15 = lane & 15, lq = lane >> 4, lk8 = lq * 8;
  const int browBase = (int)blockIdx.x * 64;
  const int row0 = browBase + wid * 16;
  const bool set1 = browBase < nx;
  const float* X = set1 ? X1 : X2;
  const int xrow = set1 ? row0 : row0 - nx;
  const float* xptr = X + (size_t)(xrow + l15) * LAT + lk8;

  f32x4 acc[8];
#pragma unroll
  for (int f = 0; f < 8; ++f) acc[f] = (f32x4){0.f, 0.f, 0.f, 0.f};

#pragma unroll
  for (int kb = 0; kb < LAT; kb += 128) {
    float4 xv[4][2];
#pragma unroll
    for (int s = 0; s < 4; ++s) {
      xv[s][0] = *(const float4*)(xptr + kb + s * 32);
      xv[s][1] = *(const float4*)(xptr + kb + s * 32 + 4);
    }
#pragma unroll
    for (int s = 0; s < 4; ++s) {
      const float vv[8] = {xv[s][0].x, xv[s][0].y, xv[s][0].z, xv[s][0].w,
                           xv[s][1].x, xv[s][1].y, xv[s][1].z, xv[s][1].w};
      bf16x8 bfr;
#pragma unroll
      for (int i = 0; i < 8; ++i) bfr[i] = (short)f2bf(vv[i]);
      const int k = kb + s * 32 + lk8;
#pragma unroll
      for (int f = 0; f < 8; ++f) {
        const bf16x8 afr = *(const bf16x8*)(W1T + (size_t)(f * 16 + l15) * LAT + k);
        acc[f] = __builtin_amdgcn_mfma_f32_16x16x32_bf16(afr, bfr, acc[f], 0, 0, 0);
      }
    }
  }
  // H[row0+l15][f*16+lq*4+r]
#pragma unroll
  for (int f = 0; f < 8; ++f) {
    ushort4 hz = {f2bf(acc[f][0]), f2bf(acc[f][1]), f2bf(acc[f][2]), f2bf(acc[f][3])};
    *(ushort4*)(H + (size_t)(row0 + l15) * HID + f * 16 + lq * 4) = hz;
  }
  // per-block column stats (64 rows): shfl pairs rows within groups of 4, then LDS
#pragma unroll
  for (int f = 0; f < 8; ++f) {
    f32x4 s = acc[f];
    f32x4 q = acc[f] * acc[f];
#pragma unroll
    for (int r = 0; r < 4; ++r) {
      s[r] += __shfl_xor(s[r], 1, 64);
      q[r] += __shfl_xor(q[r], 1, 64);
      s[r] += __shfl_xor(s[r], 2, 64);
      q[r] += __shfl_xor(q[r], 2, 64);
    }
    if ((l15 & 3) == 0) {
      *(f32x4*)&sS[wid * 4 + (l15 >> 2)][f * 16 + lq * 4] = s;
      *(f32x4*)&sQ[wid * 4 + (l15 >> 2)][f * 16 + lq * 4] = q;
    }
  }
  __syncthreads();
  if (tid < HID) {
    float s = 0.f, q = 0.f;
#pragma unroll
    for (int rr = 0; rr < 16; ++rr) { s += sS[rr][tid]; q += sQ[rr][tid]; }
    pS[(size_t)blockIdx.x * HID + tid] = s;
    pQ[(size_t)blockIdx.x * HID + tid] = q;
  }
  __syncthreads();
  // last-block-inline finalize (rocPRIM-style ticket; no spin waits)
  __threadfence();
  if (tid == 0) {
    const unsigned int old = atomicAdd(ticket, 1u);
    lastFlag = (old == (unsigned int)(nblk - 1)) ? 1u : 0u;
  }
  __syncthreads();
  if (lastFlag) {
    __threadfence();
    const int col = tid & 127;
    const bool one = tid < 128;
    const int b0 = one ? 0 : nb1;
    const int b1 = one ? nb1 : nblk;
    float s = 0.f, q = 0.f;
#pragma unroll 4
    for (int b = b0; b < b1; ++b) {
      s += pS[(size_t)b * HID + col];
      q += pQ[(size_t)b * HID + col];
    }
    const float n = one ? n1c : n2c;
    const float mean = s / n;
    const float var = q / n - mean * mean;
    const float rstd = rsqrtf(var + EPSV);
    const float scale = gamma[col] * rstd;
    const float shift = beta[col] - mean * scale;
    if (one) { sc1[col] = scale; sh1[col] = shift; }
    else     { sc2[col] = scale; sh2[col] = shift; }
  }
}

// ---------------- gemm2: Z(bf16) = relu(H*sc+sh) @ W2 + f32 row norms ----------------
__global__ __launch_bounds__(256) void k_gemm2(
    const unsigned short* __restrict__ H, int nx,
    const unsigned short* __restrict__ W2T,
    const float* __restrict__ sc1, const float* __restrict__ sh1,
    const float* __restrict__ sc2, const float* __restrict__ sh2,
    unsigned short* __restrict__ Z, float* __restrict__ nrm) {
  const int tid = threadIdx.x, wid = tid >> 6, lane = tid & 63;
  const int l15 = lane & 15, lq = lane >> 4, lk8 = lq * 8;
  const int row0 = (int)blockIdx.x * 64 + wid * 16;
  const bool set1 = row0 < nx;
  const float* sc = set1 ? sc1 : sc2;
  const float* sh = set1 ? sh1 : sh2;
  const unsigned short* hptr = H + (size_t)(row0 + l15) * HID + lk8;
  f32x4 acc[8];
#pragma unroll
  for (int f = 0; f < 8; ++f) acc[f] = (f32x4){0.f, 0.f, 0.f, 0.f};
#pragma unroll
  for (int s = 0; s < 4; ++s) {
    const int k = s * 32 + lk8;
    const bf16x8 hv = *(const bf16x8*)(hptr + s * 32);
    const float4 c0 = *(const float4*)(sc + k);
    const float4 c1 = *(const float4*)(sc + k + 4);
    const float4 d0 = *(const float4*)(sh + k);
    const float4 d1 = *(const float4*)(sh + k + 4);
    const float cc[8] = {c0.x, c0.y, c0.z, c0.w, c1.x, c1.y, c1.z, c1.w};
    const float dd[8] = {d0.x, d0.y, d0.z, d0.w, d1.x, d1.y, d1.z, d1.w};
    bf16x8 bfr;
#pragma unroll
    for (int i = 0; i < 8; ++i) {
      const float a = fmaxf(fmaf(bf2f((unsigned short)hv[i]), cc[i], dd[i]), 0.f);
      bfr[i] = (short)f2bf(a);
    }
#pragma unroll
    for (int f = 0; f < 8; ++f) {
      const bf16x8 afr = *(const bf16x8*)(W2T + (size_t)(f * 16 + l15) * HID + k);
      acc[f] = __builtin_amdgcn_mfma_f32_16x16x32_bf16(afr, bfr, acc[f], 0, 0, 0);
    }
  }
  float rn = 0.f;
#pragma unroll
  for (int f = 0; f < 8; ++f) {
    rn += acc[f][0] * acc[f][0] + acc[f][1] * acc[f][1] +
          acc[f][2] * acc[f][2] + acc[f][3] * acc[f][3];
    ushort4 z4 = {f2bf(acc[f][0]), f2bf(acc[f][1]), f2bf(acc[f][2]), f2bf(acc[f][3])};
    *(ushort4*)(Z + (size_t)(row0 + l15) * HID + f * 16 + lq * 4) = z4;
  }
  rn += __shfl_xor(rn, 16, 64);
  rn += __shfl_xor(rn, 32, 64);
  if (lane < 16) nrm[row0 + l15] = rn;
}

// ---------------- dist: D = n1[i]+n2[j]-2*Z1@Z2^T, LDS-staged wide-segment stores ----
__global__ __launch_bounds__(256) void k_dist(const unsigned short* __restrict__ Z1b,
                                              const unsigned short* __restrict__ Z2b,
                                              const float* __restrict__ n1,
                                              const float* __restrict__ n2,
                                              float* __restrict__ D, int NY) {
  __shared__ float lds[4][16][68];  // per-wave plane, pad 68 (2-way max on writes)
  const int tid = threadIdx.x;
  const int wid = tid >> 6, lane = tid & 63;
  const int wr = wid >> 1, wc = wid & 1;
  const int rowB = blockIdx.y * 128 + wr * 64;
  const int colB = blockIdx.x * 128 + wc * 64;
  const int l15 = lane & 15, lq = lane >> 4;
  const int lk = lq * 8;
  const unsigned short* Arow = Z1b + (size_t)(rowB + l15) * HID + lk;
  const unsigned short* Brow = Z2b + (size_t)(colB + l15) * HID + lk;
  f32x4 acc[4][4];
#pragma unroll
  for (int i = 0; i < 4; ++i)
#pragma unroll
    for (int j = 0; j < 4; ++j) acc[i][j] = (f32x4){0.f, 0.f, 0.f, 0.f};
#pragma unroll
  for (int s = 0; s < 4; ++s) {
    bf16x8 a[4], b[4];
#pragma unroll
    for (int i = 0; i < 4; ++i) a[i] = *(const bf16x8*)(Arow + (size_t)i * 16 * HID + s * 32);
#pragma unroll
    for (int j = 0; j < 4; ++j) b[j] = *(const bf16x8*)(Brow + (size_t)j * 16 * HID + s * 32);
#pragma unroll
    for (int i = 0; i < 4; ++i)
#pragma unroll
      for (int j = 0; j < 4; ++j)
        acc[i][j] = __builtin_amdgcn_mfma_f32_16x16x32_bf16(b[j], a[i], acc[i][j], 0, 0, 0);
  }
  // lane holds D[rowB+i*16+l15][colB+j*16+lq*4+r]
  const int cq = lq * 4;
  float na[4];
#pragma unroll
  for (int i = 0; i < 4; ++i) na[i] = n1[rowB + i * 16 + l15];
  const int h = lane >> 4;          // 0..3 (rows-within-quad for drain)
  const int cl = (lane & 15) << 2;  // 0..60 (col for drain)
#pragma unroll
  for (int i = 0; i < 4; ++i) {
#pragma unroll
    for (int j = 0; j < 4; ++j) {
      const float4 nbv = *(const float4*)(n2 + colB + j * 16 + cq);
      f32x4 ov;
      ov[0] = na[i] + nbv.x - 2.f * acc[i][j][0];
      ov[1] = na[i] + nbv.y - 2.f * acc[i][j][1];
      ov[2] = na[i] + nbv.z - 2.f * acc[i][j][2];
      ov[3] = na[i] + nbv.w - 2.f * acc[i][j][3];
      *(f32x4*)&lds[wid][l15][j * 16 + cq] = ov;
    }
    __syncthreads();  // uniform across all 4 waves; orders write->read
    float* dbase = D + (size_t)(rowB + i * 16) * NY + colB;
#pragma unroll
    for (int rr = 0; rr < 4; ++rr) {
      const int r = (rr << 2) + h;
      const f32x4 v = *(const f32x4*)&lds[wid][r][cl];
      *(f32x4*)(dbase + (size_t)r * NY + cl) = v;  // 256B contiguous per 16 lanes
    }
    __syncthreads();
  }
}

extern "C" void kernel_launch(void* const* d_in, const int* in_sizes, int n_in,
                              void* d_out, int out_size, void* d_ws, size_t ws_size,
                              hipStream_t stream) {
  const float* variations = (const float*)d_in[0];
  const float* exemplar   = (const float*)d_in[1];
  const float* w1         = (const float*)d_in[2];
  const float* gamma      = (const float*)d_in[3];
  const float* beta       = (const float*)d_in[4];
  const float* w2         = (const float*)d_in[5];
  float* D = (float*)d_out;

  const int nx = in_sizes[0] / LAT;  // 8192
  const int ny = in_sizes[1] / LAT;  // 2048
  const int nrows = nx + ny;         // 10240
  const int nblk = nrows / 64;       // 160
  const int nb1 = nx / 64;           // 128

  char* p = (char*)d_ws;
  unsigned short* Hb  = (unsigned short*)p; p += (size_t)nrows * HID * 2;
  unsigned short* Zb  = (unsigned short*)p; p += (size_t)nrows * HID * 2;
  unsigned short* W1T = (unsigned short*)p; p += (size_t)LAT * HID * 2;
  unsigned short* W2T = (unsigned short*)p; p += (size_t)HID * HID * 2;
  float* pS = (float*)p;  p += (size_t)nblk * HID * 4;
  float* pQ = (float*)p;  p += (size_t)nblk * HID * 4;
  float* sc1 = (float*)p; p += HID * 4;
  float* sh1 = (float*)p; p += HID * 4;
  float* sc2 = (float*)p; p += HID * 4;
  float* sh2 = (float*)p; p += HID * 4;
  float* nrmAll = (float*)p; p += (size_t)nrows * 4;
  unsigned int* ticket = (unsigned int*)p; p += 16;
  float* n1v = nrmAll;
  float* n2v = nrmAll + nx;
  unsigned short* Z1b = Zb;
  unsigned short* Z2b = Zb + (size_t)nx * HID;

  k_prep<<<20, 256, 0, stream>>>(w1, w2, W1T, W2T, ticket);
  k_gemm1<<<nblk, 256, 0, stream>>>(variations, exemplar, nx, W1T, Hb,
                                    pS, pQ, nb1, nblk, gamma, beta,
                                    sc1, sh1, sc2, sh2, ticket,
                                    (float)nx, (float)ny);
  k_gemm2<<<nblk, 256, 0, stream>>>(Hb, nx, W2T, sc1, sh1, sc2, sh2, Zb, nrmAll);
  dim3 dgrid(ny / 128, nx / 128);
  k_dist<<<dgrid, 256, 0, stream>>>(Z1b, Z2b, n1v, n2v, D, ny);
}